// Round 1
// baseline (200.145 us; speedup 1.0000x reference)
//
#include <hip/hip_runtime.h>
#include <hip/hip_bf16.h>
#include <math.h>

#define BB 2
#define TT 2048
#define CCH 1024
#define HH 16
#define DD 64
#define BT (BB*TT)     // 4096
#define N3 (3*CCH)     // 3072

typedef __attribute__((ext_vector_type(8))) short short8;
typedef __attribute__((ext_vector_type(4))) float f32x4;

__device__ __forceinline__ unsigned short f2bf(float f) {
  unsigned int u = __float_as_uint(f);
  unsigned int r = (u + 0x7FFFu + ((u >> 16) & 1u)) >> 16;  // RNE
  return (unsigned short)r;
}

// ---------------- transpose + f32->bf16 convert: out[c][r] = in[r][c] ----------------
__global__ __launch_bounds__(256) void k_transpose_cvt(const float* __restrict__ in,
                                                       unsigned short* __restrict__ out,
                                                       int R, int Cn) {
  __shared__ float tile[32][33];
  int tc = blockIdx.x * 32;
  int tr = blockIdx.y * 32;
  int lx = threadIdx.x & 31;
  int ly = threadIdx.x >> 5;  // 0..7
#pragma unroll
  for (int i = 0; i < 32; i += 8)
    tile[ly + i][lx] = in[(size_t)(tr + ly + i) * Cn + tc + lx];
  __syncthreads();
#pragma unroll
  for (int i = 0; i < 32; i += 8)
    out[(size_t)(tc + ly + i) * R + tr + lx] = f2bf(tile[lx][ly + i]);
}

// ---------------- QKV GEMM: x[4096][1024] f32  @  Wt[3072][1024] bf16 -> Q,K,Vt bf16 ----------------
__global__ __launch_bounds__(256) void k_qkv_gemm(const float* __restrict__ X,
                                                  const unsigned short* __restrict__ Wt,
                                                  const float* __restrict__ bias,
                                                  unsigned short* __restrict__ Qo,
                                                  unsigned short* __restrict__ Ko,
                                                  unsigned short* __restrict__ Vto) {
  __shared__ unsigned short As[128][40];
  __shared__ unsigned short Bs[128][40];
  int tid = threadIdx.x;
  int mb = blockIdx.x * 128;
  int nb = blockIdx.y * 128;
  int wid = tid >> 6, lane = tid & 63;
  int wr = (wid >> 1) * 64, wc = (wid & 1) * 64;
  int l15 = lane & 15, l4 = lane >> 4;
  f32x4 acc[4][4];
#pragma unroll
  for (int a = 0; a < 4; ++a)
#pragma unroll
    for (int b = 0; b < 4; ++b)
#pragma unroll
      for (int j = 0; j < 4; ++j) acc[a][b][j] = 0.0f;

  for (int kb = 0; kb < CCH; kb += 32) {
    __syncthreads();
    // stage A: 128x32 f32 -> bf16
#pragma unroll
    for (int i = 0; i < 4; ++i) {
      int idx = tid + i * 256;
      int row = idx >> 3, c4 = idx & 7;
      const float4 v = *(const float4*)(X + (size_t)(mb + row) * CCH + kb + c4 * 4);
      ushort4 b4;
      b4.x = f2bf(v.x); b4.y = f2bf(v.y); b4.z = f2bf(v.z); b4.w = f2bf(v.w);
      *(ushort4*)(&As[row][c4 * 4]) = b4;
    }
    // stage B (already bf16): 128x32
#pragma unroll
    for (int i = 0; i < 2; ++i) {
      int idx = tid + i * 256;
      int row = idx >> 2, c8 = idx & 3;
      *(short8*)(&Bs[row][c8 * 8]) = *(const short8*)(Wt + (size_t)(nb + row) * CCH + kb + c8 * 8);
    }
    __syncthreads();
    short8 af[4], bfr[4];
#pragma unroll
    for (int mt = 0; mt < 4; ++mt) af[mt] = *(const short8*)(&As[wr + mt * 16 + l15][l4 * 8]);
#pragma unroll
    for (int nt = 0; nt < 4; ++nt) bfr[nt] = *(const short8*)(&Bs[wc + nt * 16 + l15][l4 * 8]);
#pragma unroll
    for (int mt = 0; mt < 4; ++mt)
#pragma unroll
      for (int nt = 0; nt < 4; ++nt)
        acc[mt][nt] = __builtin_amdgcn_mfma_f32_16x16x32_bf16(af[mt], bfr[nt], acc[mt][nt], 0, 0, 0);
  }

  // epilogue: scatter into Q[B,H,T,D], K[B,H,T,D], Vt[B,H,D,T]
#pragma unroll
  for (int mt = 0; mt < 4; ++mt) {
#pragma unroll
    for (int nt = 0; nt < 4; ++nt) {
      int gcol = nb + wc + nt * 16 + l15;        // 0..3071
      int which = gcol >> 10;
      int cc = gcol & 1023;
      int h = cc >> 6, d = cc & 63;
      float bv = bias[gcol];
#pragma unroll
      for (int j = 0; j < 4; ++j) {
        int grow = mb + wr + mt * 16 + l4 * 4 + j;  // 0..4095
        int b = grow >> 11, t = grow & 2047;
        unsigned short val = f2bf(acc[mt][nt][j] + bv);
        size_t bh = (size_t)(b * HH + h);
        if (which == 0)      Qo[(bh * TT + t) * DD + d] = val;
        else if (which == 1) Ko[(bh * TT + t) * DD + d] = val;
        else                 Vto[(bh * DD + d) * TT + t] = val;
      }
    }
  }
}

// ---------------- causal flash attention ----------------
__global__ __launch_bounds__(256) void k_attn(const unsigned short* __restrict__ Qb,
                                              const unsigned short* __restrict__ Kb,
                                              const unsigned short* __restrict__ Vtb,
                                              unsigned short* __restrict__ Y) {
  __shared__ unsigned short Ks[64][72];
  __shared__ unsigned short Vs[64][72];
  __shared__ unsigned short Ps[4][32][72];
  int tid = threadIdx.x;
  int qb = blockIdx.x * 128;
  int bh = blockIdx.y;
  const unsigned short* Qp = Qb + (size_t)bh * TT * DD;
  const unsigned short* Kp = Kb + (size_t)bh * TT * DD;
  const unsigned short* Vp = Vtb + (size_t)bh * DD * TT;
  int wid = tid >> 6, lane = tid & 63;
  int l15 = lane & 15, l4 = lane >> 4;
  int qwb = qb + wid * 32;

  short8 qa[2][2];
#pragma unroll
  for (int rt = 0; rt < 2; ++rt)
#pragma unroll
    for (int kc = 0; kc < 2; ++kc)
      qa[rt][kc] = *(const short8*)(Qp + (size_t)(qwb + rt * 16 + l15) * DD + kc * 32 + l4 * 8);

  f32x4 o[2][4];
  f32x4 mrun[2], lrun[2];
#pragma unroll
  for (int rt = 0; rt < 2; ++rt) {
#pragma unroll
    for (int j = 0; j < 4; ++j) { mrun[rt][j] = -1e30f; lrun[rt][j] = 0.0f; }
#pragma unroll
    for (int dc = 0; dc < 4; ++dc)
#pragma unroll
      for (int j = 0; j < 4; ++j) o[rt][dc][j] = 0.0f;
  }

  for (int kvb = 0; kvb < qb + 128; kvb += 64) {
    __syncthreads();
    // stage K tile [64 kv][64 d] and Vt tile [64 d][64 kv]
#pragma unroll
    for (int i = 0; i < 2; ++i) {
      int idx = tid + i * 256;
      int row = idx >> 3, c8 = idx & 7;
      *(short8*)(&Ks[row][c8 * 8]) = *(const short8*)(Kp + (size_t)(kvb + row) * DD + c8 * 8);
      *(short8*)(&Vs[row][c8 * 8]) = *(const short8*)(Vp + (size_t)row * TT + kvb + c8 * 8);
    }
    __syncthreads();
    if (kvb > qwb + 31) continue;   // wave-uniform skip; barriers stay aligned

    // S = Q K^T
    f32x4 s[2][4];
#pragma unroll
    for (int rt = 0; rt < 2; ++rt)
#pragma unroll
      for (int ct = 0; ct < 4; ++ct)
#pragma unroll
        for (int j = 0; j < 4; ++j) s[rt][ct][j] = 0.0f;
#pragma unroll
    for (int ct = 0; ct < 4; ++ct) {
#pragma unroll
      for (int kc = 0; kc < 2; ++kc) {
        short8 kf = *(const short8*)(&Ks[ct * 16 + l15][kc * 32 + l4 * 8]);
#pragma unroll
        for (int rt = 0; rt < 2; ++rt)
          s[rt][ct] = __builtin_amdgcn_mfma_f32_16x16x32_bf16(qa[rt][kc], kf, s[rt][ct], 0, 0, 0);
      }
    }

#pragma unroll
    for (int rt = 0; rt < 2; ++rt) {
      int q0 = qwb + rt * 16 + l4 * 4;
      f32x4 tm;
#pragma unroll
      for (int j = 0; j < 4; ++j) tm[j] = -1e30f;
#pragma unroll
      for (int ct = 0; ct < 4; ++ct) {
        int kg = kvb + ct * 16 + l15;
#pragma unroll
        for (int j = 0; j < 4; ++j) {
          float v = (kg <= q0 + j) ? s[rt][ct][j] * 0.125f : -1e30f;
          s[rt][ct][j] = v;
          tm[j] = fmaxf(tm[j], v);
        }
      }
#pragma unroll
      for (int msk = 1; msk < 16; msk <<= 1)
#pragma unroll
        for (int j = 0; j < 4; ++j) tm[j] = fmaxf(tm[j], __shfl_xor(tm[j], msk));

      f32x4 alpha, tsum;
#pragma unroll
      for (int j = 0; j < 4; ++j) {
        float mn = fmaxf(mrun[rt][j], tm[j]);
        alpha[j] = __expf(mrun[rt][j] - mn);
        mrun[rt][j] = mn;
        tsum[j] = 0.0f;
      }
#pragma unroll
      for (int ct = 0; ct < 4; ++ct)
#pragma unroll
        for (int j = 0; j < 4; ++j) {
          float p = __expf(s[rt][ct][j] - mrun[rt][j]);
          s[rt][ct][j] = p;
          tsum[j] += p;
        }
#pragma unroll
      for (int msk = 1; msk < 16; msk <<= 1)
#pragma unroll
        for (int j = 0; j < 4; ++j) tsum[j] += __shfl_xor(tsum[j], msk);
#pragma unroll
      for (int j = 0; j < 4; ++j) lrun[rt][j] = lrun[rt][j] * alpha[j] + tsum[j];
#pragma unroll
      for (int dc = 0; dc < 4; ++dc)
#pragma unroll
        for (int j = 0; j < 4; ++j) o[rt][dc][j] *= alpha[j];
      // P -> LDS (per-wave buffer), bf16
#pragma unroll
      for (int ct = 0; ct < 4; ++ct)
#pragma unroll
        for (int j = 0; j < 4; ++j)
          Ps[wid][rt * 16 + l4 * 4 + j][ct * 16 + l15] = f2bf(s[rt][ct][j]);
    }

    // O += P V   (Vt rows give B-operand fragments)
    short8 pa[2][2];
#pragma unroll
    for (int rt = 0; rt < 2; ++rt)
#pragma unroll
      for (int kc = 0; kc < 2; ++kc)
        pa[rt][kc] = *(const short8*)(&Ps[wid][rt * 16 + l15][kc * 32 + l4 * 8]);
#pragma unroll
    for (int dc = 0; dc < 4; ++dc)
#pragma unroll
      for (int kc = 0; kc < 2; ++kc) {
        short8 vf = *(const short8*)(&Vs[dc * 16 + l15][kc * 32 + l4 * 8]);
#pragma unroll
        for (int rt = 0; rt < 2; ++rt)
          o[rt][dc] = __builtin_amdgcn_mfma_f32_16x16x32_bf16(pa[rt][kc], vf, o[rt][dc], 0, 0, 0);
      }
  }

  // normalize + store y[b][t][h*64+d]
  int b = bh >> 4, h = bh & 15;
#pragma unroll
  for (int rt = 0; rt < 2; ++rt)
#pragma unroll
    for (int j = 0; j < 4; ++j) {
      float inv = 1.0f / lrun[rt][j];
      int t = qwb + rt * 16 + l4 * 4 + j;
#pragma unroll
      for (int dc = 0; dc < 4; ++dc) {
        int d = dc * 16 + l15;
        Y[(size_t)(b * TT + t) * CCH + h * DD + d] = f2bf(o[rt][dc][j] * inv);
      }
    }
}

// ---------------- proj GEMM: y[4096][1024] bf16 @ Wt_proj[1024][1024] bf16 + bias -> f32 out ----------------
__global__ __launch_bounds__(256) void k_proj_gemm(const unsigned short* __restrict__ Yb,
                                                   const unsigned short* __restrict__ Wt,
                                                   const float* __restrict__ bias,
                                                   float* __restrict__ Out) {
  __shared__ unsigned short As[128][40];
  __shared__ unsigned short Bs[128][40];
  int tid = threadIdx.x;
  int mb = blockIdx.x * 128;
  int nb = blockIdx.y * 128;
  int wid = tid >> 6, lane = tid & 63;
  int wr = (wid >> 1) * 64, wc = (wid & 1) * 64;
  int l15 = lane & 15, l4 = lane >> 4;
  f32x4 acc[4][4];
#pragma unroll
  for (int a = 0; a < 4; ++a)
#pragma unroll
    for (int b = 0; b < 4; ++b)
#pragma unroll
      for (int j = 0; j < 4; ++j) acc[a][b][j] = 0.0f;

  for (int kb = 0; kb < CCH; kb += 32) {
    __syncthreads();
#pragma unroll
    for (int i = 0; i < 2; ++i) {
      int idx = tid + i * 256;
      int row = idx >> 2, c8 = idx & 3;
      *(short8*)(&As[row][c8 * 8]) = *(const short8*)(Yb + (size_t)(mb + row) * CCH + kb + c8 * 8);
      *(short8*)(&Bs[row][c8 * 8]) = *(const short8*)(Wt + (size_t)(nb + row) * CCH + kb + c8 * 8);
    }
    __syncthreads();
    short8 af[4], bfr[4];
#pragma unroll
    for (int mt = 0; mt < 4; ++mt) af[mt] = *(const short8*)(&As[wr + mt * 16 + l15][l4 * 8]);
#pragma unroll
    for (int nt = 0; nt < 4; ++nt) bfr[nt] = *(const short8*)(&Bs[wc + nt * 16 + l15][l4 * 8]);
#pragma unroll
    for (int mt = 0; mt < 4; ++mt)
#pragma unroll
      for (int nt = 0; nt < 4; ++nt)
        acc[mt][nt] = __builtin_amdgcn_mfma_f32_16x16x32_bf16(af[mt], bfr[nt], acc[mt][nt], 0, 0, 0);
  }

#pragma unroll
  for (int mt = 0; mt < 4; ++mt) {
#pragma unroll
    for (int nt = 0; nt < 4; ++nt) {
      int gcol = nb + wc + nt * 16 + l15;
      float bv = bias[gcol];
#pragma unroll
      for (int j = 0; j < 4; ++j) {
        int grow = mb + wr + mt * 16 + l4 * 4 + j;
        Out[(size_t)grow * CCH + gcol] = acc[mt][nt][j] + bv;
      }
    }
  }
}

extern "C" void kernel_launch(void* const* d_in, const int* in_sizes, int n_in,
                              void* d_out, int out_size, void* d_ws, size_t ws_size,
                              hipStream_t stream) {
  const float* x      = (const float*)d_in[0];
  const float* W_qkv  = (const float*)d_in[1];
  const float* b_qkv  = (const float*)d_in[2];
  const float* W_proj = (const float*)d_in[3];
  const float* b_proj = (const float*)d_in[4];
  float* out = (float*)d_out;

  char* ws = (char*)d_ws;
  size_t off = 0;
  unsigned short* Wt_qkv  = (unsigned short*)(ws + off); off += (size_t)N3 * CCH * 2;  // 6.3 MB
  unsigned short* Wt_proj = (unsigned short*)(ws + off); off += (size_t)CCH * CCH * 2; // 2.1 MB
  unsigned short* Qb      = (unsigned short*)(ws + off); off += (size_t)BT * CCH * 2;  // 8.4 MB
  unsigned short* Kb      = (unsigned short*)(ws + off); off += (size_t)BT * CCH * 2;  // 8.4 MB
  unsigned short* Vt      = (unsigned short*)(ws + off); off += (size_t)BT * CCH * 2;  // 8.4 MB
  unsigned short* Yb      = (unsigned short*)(ws + off); off += (size_t)BT * CCH * 2;  // 8.4 MB  (total ~42 MB)

  k_transpose_cvt<<<dim3(N3 / 32, CCH / 32), 256, 0, stream>>>(W_qkv, Wt_qkv, CCH, N3);
  k_transpose_cvt<<<dim3(CCH / 32, CCH / 32), 256, 0, stream>>>(W_proj, Wt_proj, CCH, CCH);
  k_qkv_gemm<<<dim3(BT / 128, N3 / 128), 256, 0, stream>>>(x, Wt_qkv, b_qkv, Qb, Kb, Vt);
  k_attn<<<dim3(TT / 128, BB * HH), 256, 0, stream>>>(Qb, Kb, Vt, Yb);
  k_proj_gemm<<<dim3(BT / 128, CCH / 128), 256, 0, stream>>>(Yb, Wt_proj, b_proj, out);
}

// Round 2
// 176.536 us; speedup vs baseline: 1.1337x; 1.1337x over previous
//
#include <hip/hip_runtime.h>
#include <hip/hip_bf16.h>
#include <math.h>

#define BB 2
#define TT 2048
#define CCH 1024
#define HH 16
#define DD 64
#define BT (BB*TT)     // 4096
#define N3 (3*CCH)     // 3072
#define NJOBS 40       // sum over 16 q-tiles of ceil((qt+1)/4)

typedef __attribute__((ext_vector_type(8))) short short8;
typedef __attribute__((ext_vector_type(4))) float f32x4;

__device__ __forceinline__ unsigned short f2bf(float f) {
  unsigned int u = __float_as_uint(f);
  unsigned int r = (u + 0x7FFFu + ((u >> 16) & 1u)) >> 16;  // RNE
  return (unsigned short)r;
}
__device__ __forceinline__ float bf2f(unsigned short u) {
  return __uint_as_float(((unsigned int)u) << 16);
}
// job-base for q-tile qt: base = qt + 2a(a-1) + a*b, a=qt>>2, b=qt&3
__device__ __forceinline__ int jbase(int qt) {
  int a = qt >> 2, b = qt & 3;
  return qt + 2 * a * (a - 1) + a * b;
}

// ---------------- transpose + f32->bf16 convert: out[c][r] = in[r][c] ----------------
__global__ __launch_bounds__(256) void k_transpose_cvt(const float* __restrict__ in,
                                                       unsigned short* __restrict__ out,
                                                       int R, int Cn) {
  __shared__ float tile[32][33];
  int tc = blockIdx.x * 32;
  int tr = blockIdx.y * 32;
  int lx = threadIdx.x & 31;
  int ly = threadIdx.x >> 5;  // 0..7
#pragma unroll
  for (int i = 0; i < 32; i += 8)
    tile[ly + i][lx] = in[(size_t)(tr + ly + i) * Cn + tc + lx];
  __syncthreads();
#pragma unroll
  for (int i = 0; i < 32; i += 8)
    out[(size_t)(tc + ly + i) * R + tr + lx] = f2bf(tile[lx][ly + i]);
}

// ---------------- QKV GEMM: x[4096][1024] f32  @  Wt[3072][1024] bf16 -> Q,K,Vt bf16 ----------------
__global__ __launch_bounds__(256) void k_qkv_gemm(const float* __restrict__ X,
                                                  const unsigned short* __restrict__ Wt,
                                                  const float* __restrict__ bias,
                                                  unsigned short* __restrict__ Qo,
                                                  unsigned short* __restrict__ Ko,
                                                  unsigned short* __restrict__ Vto) {
  __shared__ unsigned short As[128][40];
  __shared__ unsigned short Bs[128][40];
  int tid = threadIdx.x;
  int mb = blockIdx.x * 128;
  int nb = blockIdx.y * 128;
  int wid = tid >> 6, lane = tid & 63;
  int wr = (wid >> 1) * 64, wc = (wid & 1) * 64;
  int l15 = lane & 15, l4 = lane >> 4;
  f32x4 acc[4][4];
#pragma unroll
  for (int a = 0; a < 4; ++a)
#pragma unroll
    for (int b = 0; b < 4; ++b)
#pragma unroll
      for (int j = 0; j < 4; ++j) acc[a][b][j] = 0.0f;

  for (int kb = 0; kb < CCH; kb += 32) {
    __syncthreads();
#pragma unroll
    for (int i = 0; i < 4; ++i) {
      int idx = tid + i * 256;
      int row = idx >> 3, c4 = idx & 7;
      const float4 v = *(const float4*)(X + (size_t)(mb + row) * CCH + kb + c4 * 4);
      ushort4 b4;
      b4.x = f2bf(v.x); b4.y = f2bf(v.y); b4.z = f2bf(v.z); b4.w = f2bf(v.w);
      *(ushort4*)(&As[row][c4 * 4]) = b4;
    }
#pragma unroll
    for (int i = 0; i < 2; ++i) {
      int idx = tid + i * 256;
      int row = idx >> 2, c8 = idx & 3;
      *(short8*)(&Bs[row][c8 * 8]) = *(const short8*)(Wt + (size_t)(nb + row) * CCH + kb + c8 * 8);
    }
    __syncthreads();
    short8 af[4], bfr[4];
#pragma unroll
    for (int mt = 0; mt < 4; ++mt) af[mt] = *(const short8*)(&As[wr + mt * 16 + l15][l4 * 8]);
#pragma unroll
    for (int nt = 0; nt < 4; ++nt) bfr[nt] = *(const short8*)(&Bs[wc + nt * 16 + l15][l4 * 8]);
#pragma unroll
    for (int mt = 0; mt < 4; ++mt)
#pragma unroll
      for (int nt = 0; nt < 4; ++nt)
        acc[mt][nt] = __builtin_amdgcn_mfma_f32_16x16x32_bf16(af[mt], bfr[nt], acc[mt][nt], 0, 0, 0);
  }

#pragma unroll
  for (int mt = 0; mt < 4; ++mt) {
#pragma unroll
    for (int nt = 0; nt < 4; ++nt) {
      int gcol = nb + wc + nt * 16 + l15;        // 0..3071
      int which = gcol >> 10;
      int cc = gcol & 1023;
      int h = cc >> 6, d = cc & 63;
      float bv = bias[gcol];
#pragma unroll
      for (int j = 0; j < 4; ++j) {
        int grow = mb + wr + mt * 16 + l4 * 4 + j;  // 0..4095
        int b = grow >> 11, t = grow & 2047;
        unsigned short val = f2bf(acc[mt][nt][j] + bv);
        size_t bh = (size_t)(b * HH + h);
        if (which == 0)      Qo[(bh * TT + t) * DD + d] = val;
        else if (which == 1) Ko[(bh * TT + t) * DD + d] = val;
        else                 Vto[(bh * DD + d) * TT + t] = val;
      }
    }
  }
}

// ---------------- causal flash attention, KV-chunked partials ----------------
// grid: (NJOBS, B*H). job jx -> (qt, chunk of 8 KV-tiles). Writes unnormalized
// partial O (bf16) + running m,l (f32) per row for a later combine pass.
__global__ __launch_bounds__(256) void k_attn(const unsigned short* __restrict__ Qb,
                                              const unsigned short* __restrict__ Kb,
                                              const unsigned short* __restrict__ Vtb,
                                              unsigned short* __restrict__ PO,
                                              float* __restrict__ Pm,
                                              float* __restrict__ Pl) {
  __shared__ unsigned short Ks[2][64][72];
  __shared__ unsigned short Vs[2][64][72];
  __shared__ unsigned short Ps[4][32][72];
  int tid = threadIdx.x;
  int jx = blockIdx.x;   // 0..39
  int bh = blockIdx.y;
  // decode q-tile + chunk from flat job index
  int qt = 0;
#pragma unroll
  for (int q = 1; q < 16; ++q)
    if (jx >= jbase(q)) qt = q;
  int chunk = jx - jbase(qt);
  int t0 = chunk * 8;                 // first 64-wide KV tile
  int t1 = min(t0 + 8, (qt + 1) * 2); // one past last
  size_t job = (size_t)bh * NJOBS + jx;

  const unsigned short* Qp = Qb + (size_t)bh * TT * DD;
  const unsigned short* Kp = Kb + (size_t)bh * TT * DD;
  const unsigned short* Vp = Vtb + (size_t)bh * DD * TT;
  int wid = tid >> 6, lane = tid & 63;
  int l15 = lane & 15, l4 = lane >> 4;
  int qwb = qt * 128 + wid * 32;      // this wave's first q row

  short8 qa[2][2];
#pragma unroll
  for (int rt = 0; rt < 2; ++rt)
#pragma unroll
    for (int kc = 0; kc < 2; ++kc)
      qa[rt][kc] = *(const short8*)(Qp + (size_t)(qwb + rt * 16 + l15) * DD + kc * 32 + l4 * 8);

  f32x4 o[2][4];
  f32x4 mrun[2], lrun[2];
#pragma unroll
  for (int rt = 0; rt < 2; ++rt) {
#pragma unroll
    for (int j = 0; j < 4; ++j) { mrun[rt][j] = -1e30f; lrun[rt][j] = 0.0f; }
#pragma unroll
    for (int dc = 0; dc < 4; ++dc)
#pragma unroll
      for (int j = 0; j < 4; ++j) o[rt][dc][j] = 0.0f;
  }

  // prologue: stage tile t0 into buffer 0
  short8 rk[2], rv[2];
#pragma unroll
  for (int i = 0; i < 2; ++i) {
    int idx = tid + i * 256;
    int row = idx >> 3, c8 = idx & 7;
    rk[i] = *(const short8*)(Kp + (size_t)(t0 * 64 + row) * DD + c8 * 8);
    rv[i] = *(const short8*)(Vp + (size_t)row * TT + t0 * 64 + c8 * 8);
  }
#pragma unroll
  for (int i = 0; i < 2; ++i) {
    int idx = tid + i * 256;
    int row = idx >> 3, c8 = idx & 7;
    *(short8*)(&Ks[0][row][c8 * 8]) = rk[i];
    *(short8*)(&Vs[0][row][c8 * 8]) = rv[i];
  }

  int buf = 0;
  for (int t = t0; t < t1; ++t) {
    __syncthreads();                  // staged writes for `buf` visible
    int kvb = t * 64;
    bool havenext = (t + 1 < t1);
    if (havenext) {                   // issue next tile's loads early (latency hides under compute)
      int kvb2 = (t + 1) * 64;
#pragma unroll
      for (int i = 0; i < 2; ++i) {
        int idx = tid + i * 256;
        int row = idx >> 3, c8 = idx & 7;
        rk[i] = *(const short8*)(Kp + (size_t)(kvb2 + row) * DD + c8 * 8);
        rv[i] = *(const short8*)(Vp + (size_t)row * TT + kvb2 + c8 * 8);
      }
    }

    if (kvb <= qwb + 31) {            // wave-uniform: any unmasked element in tile?
      // S = Q K^T
      f32x4 s[2][4];
#pragma unroll
      for (int rt = 0; rt < 2; ++rt)
#pragma unroll
        for (int ct = 0; ct < 4; ++ct)
#pragma unroll
          for (int j = 0; j < 4; ++j) s[rt][ct][j] = 0.0f;
#pragma unroll
      for (int ct = 0; ct < 4; ++ct) {
#pragma unroll
        for (int kc = 0; kc < 2; ++kc) {
          short8 kf = *(const short8*)(&Ks[buf][ct * 16 + l15][kc * 32 + l4 * 8]);
#pragma unroll
          for (int rt = 0; rt < 2; ++rt)
            s[rt][ct] = __builtin_amdgcn_mfma_f32_16x16x32_bf16(qa[rt][kc], kf, s[rt][ct], 0, 0, 0);
        }
      }

#pragma unroll
      for (int rt = 0; rt < 2; ++rt) {
        int q0 = qwb + rt * 16 + l4 * 4;
        f32x4 tm;
#pragma unroll
        for (int j = 0; j < 4; ++j) tm[j] = -1e30f;
#pragma unroll
        for (int ct = 0; ct < 4; ++ct) {
          int kg = kvb + ct * 16 + l15;
#pragma unroll
          for (int j = 0; j < 4; ++j) {
            float v = (kg <= q0 + j) ? s[rt][ct][j] * 0.125f : -1e30f;
            s[rt][ct][j] = v;
            tm[j] = fmaxf(tm[j], v);
          }
        }
#pragma unroll
        for (int msk = 1; msk < 16; msk <<= 1)
#pragma unroll
          for (int j = 0; j < 4; ++j) tm[j] = fmaxf(tm[j], __shfl_xor(tm[j], msk));

        f32x4 alpha, tsum;
#pragma unroll
        for (int j = 0; j < 4; ++j) {
          float mn = fmaxf(mrun[rt][j], tm[j]);
          alpha[j] = __expf(mrun[rt][j] - mn);
          mrun[rt][j] = mn;
          tsum[j] = 0.0f;
        }
#pragma unroll
        for (int ct = 0; ct < 4; ++ct)
#pragma unroll
          for (int j = 0; j < 4; ++j) {
            float p = __expf(s[rt][ct][j] - mrun[rt][j]);
            s[rt][ct][j] = p;
            tsum[j] += p;
          }
#pragma unroll
        for (int msk = 1; msk < 16; msk <<= 1)
#pragma unroll
          for (int j = 0; j < 4; ++j) tsum[j] += __shfl_xor(tsum[j], msk);
#pragma unroll
        for (int j = 0; j < 4; ++j) lrun[rt][j] = lrun[rt][j] * alpha[j] + tsum[j];
#pragma unroll
        for (int dc = 0; dc < 4; ++dc)
#pragma unroll
          for (int j = 0; j < 4; ++j) o[rt][dc][j] *= alpha[j];
#pragma unroll
        for (int ct = 0; ct < 4; ++ct)
#pragma unroll
          for (int j = 0; j < 4; ++j)
            Ps[wid][rt * 16 + l4 * 4 + j][ct * 16 + l15] = f2bf(s[rt][ct][j]);
      }

      // O += P V
      short8 pa[2][2];
#pragma unroll
      for (int rt = 0; rt < 2; ++rt)
#pragma unroll
        for (int kc = 0; kc < 2; ++kc)
          pa[rt][kc] = *(const short8*)(&Ps[wid][rt * 16 + l15][kc * 32 + l4 * 8]);
#pragma unroll
      for (int dc = 0; dc < 4; ++dc)
#pragma unroll
        for (int kc = 0; kc < 2; ++kc) {
          short8 vf = *(const short8*)(&Vs[buf][dc * 16 + l15][kc * 32 + l4 * 8]);
#pragma unroll
          for (int rt = 0; rt < 2; ++rt)
            o[rt][dc] = __builtin_amdgcn_mfma_f32_16x16x32_bf16(pa[rt][kc], vf, o[rt][dc], 0, 0, 0);
        }
    }

    if (havenext) {                   // write staged regs into the other buffer
#pragma unroll
      for (int i = 0; i < 2; ++i) {
        int idx = tid + i * 256;
        int row = idx >> 3, c8 = idx & 7;
        *(short8*)(&Ks[buf ^ 1][row][c8 * 8]) = rk[i];
        *(short8*)(&Vs[buf ^ 1][row][c8 * 8]) = rv[i];
      }
    }
    buf ^= 1;
  }

  // write unnormalized partial O (bf16) + m,l
#pragma unroll
  for (int rt = 0; rt < 2; ++rt)
#pragma unroll
    for (int j = 0; j < 4; ++j) {
      int row = wid * 32 + rt * 16 + l4 * 4 + j;
#pragma unroll
      for (int dc = 0; dc < 4; ++dc) {
        int d = dc * 16 + l15;
        PO[(job * 128 + row) * 64 + d] = f2bf(o[rt][dc][j]);
      }
      if (l15 == 0) {
        Pm[job * 128 + row] = mrun[rt][j];
        Pl[job * 128 + row] = lrun[rt][j];
      }
    }
}

// ---------------- combine partials -> Yb bf16 ----------------
__global__ __launch_bounds__(256) void k_attn_combine(const unsigned short* __restrict__ PO,
                                                      const float* __restrict__ Pm,
                                                      const float* __restrict__ Pl,
                                                      unsigned short* __restrict__ Y) {
  int qt = blockIdx.x, bh = blockIdx.y;
  int nc = (qt >> 2) + 1;
  size_t job0 = (size_t)bh * NJOBS + jbase(qt);
  int tid = threadIdx.x;
  int row = tid >> 1, half = tid & 1;

  float m[4], l[4];
  float M = -1e30f;
  for (int c = 0; c < nc; ++c) {
    m[c] = Pm[(job0 + c) * 128 + row];
    l[c] = Pl[(job0 + c) * 128 + row];
    M = fmaxf(M, m[c]);
  }
  float L = 0.0f, w[4];
  for (int c = 0; c < nc; ++c) {
    w[c] = __expf(m[c] - M);
    L += l[c] * w[c];
  }
  float inv = 1.0f / L;

  float acc[32];
#pragma unroll
  for (int j = 0; j < 32; ++j) acc[j] = 0.0f;
  for (int c = 0; c < nc; ++c) {
    const unsigned short* p = PO + ((job0 + c) * 128 + row) * 64 + half * 32;
    float wc = w[c];
#pragma unroll
    for (int k = 0; k < 4; ++k) {
      short8 v = *(const short8*)(p + k * 8);
#pragma unroll
      for (int j = 0; j < 8; ++j) acc[k * 8 + j] += wc * bf2f((unsigned short)v[j]);
    }
  }
  int b = bh >> 4, h = bh & 15;
  int t = qt * 128 + row;
  unsigned short* yp = Y + ((size_t)(b * TT + t)) * CCH + h * DD + half * 32;
#pragma unroll
  for (int k = 0; k < 4; ++k) {
    short8 wv;
#pragma unroll
    for (int j = 0; j < 8; ++j) wv[j] = (short)f2bf(acc[k * 8 + j] * inv);
    *(short8*)(yp + k * 8) = wv;
  }
}

// ---------------- proj GEMM: y[4096][1024] bf16 @ Wt_proj[1024][1024] bf16 + bias -> f32 out ----------------
__global__ __launch_bounds__(256) void k_proj_gemm(const unsigned short* __restrict__ Yb,
                                                   const unsigned short* __restrict__ Wt,
                                                   const float* __restrict__ bias,
                                                   float* __restrict__ Out) {
  __shared__ unsigned short As[128][40];
  __shared__ unsigned short Bs[128][40];
  int tid = threadIdx.x;
  int mb = blockIdx.x * 128;
  int nb = blockIdx.y * 128;
  int wid = tid >> 6, lane = tid & 63;
  int wr = (wid >> 1) * 64, wc = (wid & 1) * 64;
  int l15 = lane & 15, l4 = lane >> 4;
  f32x4 acc[4][4];
#pragma unroll
  for (int a = 0; a < 4; ++a)
#pragma unroll
    for (int b = 0; b < 4; ++b)
#pragma unroll
      for (int j = 0; j < 4; ++j) acc[a][b][j] = 0.0f;

  for (int kb = 0; kb < CCH; kb += 32) {
    __syncthreads();
#pragma unroll
    for (int i = 0; i < 2; ++i) {
      int idx = tid + i * 256;
      int row = idx >> 2, c8 = idx & 3;
      *(short8*)(&As[row][c8 * 8]) = *(const short8*)(Yb + (size_t)(mb + row) * CCH + kb + c8 * 8);
      *(short8*)(&Bs[row][c8 * 8]) = *(const short8*)(Wt + (size_t)(nb + row) * CCH + kb + c8 * 8);
    }
    __syncthreads();
    short8 af[4], bfr[4];
#pragma unroll
    for (int mt = 0; mt < 4; ++mt) af[mt] = *(const short8*)(&As[wr + mt * 16 + l15][l4 * 8]);
#pragma unroll
    for (int nt = 0; nt < 4; ++nt) bfr[nt] = *(const short8*)(&Bs[wc + nt * 16 + l15][l4 * 8]);
#pragma unroll
    for (int mt = 0; mt < 4; ++mt)
#pragma unroll
      for (int nt = 0; nt < 4; ++nt)
        acc[mt][nt] = __builtin_amdgcn_mfma_f32_16x16x32_bf16(af[mt], bfr[nt], acc[mt][nt], 0, 0, 0);
  }

#pragma unroll
  for (int mt = 0; mt < 4; ++mt) {
#pragma unroll
    for (int nt = 0; nt < 4; ++nt) {
      int gcol = nb + wc + nt * 16 + l15;
      float bv = bias[gcol];
#pragma unroll
      for (int j = 0; j < 4; ++j) {
        int grow = mb + wr + mt * 16 + l4 * 4 + j;
        Out[(size_t)grow * CCH + gcol] = acc[mt][nt][j] + bv;
      }
    }
  }
}

extern "C" void kernel_launch(void* const* d_in, const int* in_sizes, int n_in,
                              void* d_out, int out_size, void* d_ws, size_t ws_size,
                              hipStream_t stream) {
  const float* x      = (const float*)d_in[0];
  const float* W_qkv  = (const float*)d_in[1];
  const float* b_qkv  = (const float*)d_in[2];
  const float* W_proj = (const float*)d_in[3];
  const float* b_proj = (const float*)d_in[4];
  float* out = (float*)d_out;

  char* ws = (char*)d_ws;
  size_t off = 0;
  unsigned short* Wt_qkv  = (unsigned short*)(ws + off); off += (size_t)N3 * CCH * 2;   // 6.3 MB
  unsigned short* Wt_proj = (unsigned short*)(ws + off); off += (size_t)CCH * CCH * 2;  // 2.1 MB
  unsigned short* Qb      = (unsigned short*)(ws + off); off += (size_t)BT * CCH * 2;   // 8.4 MB
  unsigned short* Kb      = (unsigned short*)(ws + off); off += (size_t)BT * CCH * 2;   // 8.4 MB
  unsigned short* Vt      = (unsigned short*)(ws + off); off += (size_t)BT * CCH * 2;   // 8.4 MB
  unsigned short* Yb      = (unsigned short*)(ws + off); off += (size_t)BT * CCH * 2;   // 8.4 MB
  unsigned short* PO      = (unsigned short*)(ws + off); off += (size_t)32 * NJOBS * 128 * 64 * 2; // 21 MB
  float*          Pm      = (float*)(ws + off);          off += (size_t)32 * NJOBS * 128 * 4;      // 0.66 MB
  float*          Pl      = (float*)(ws + off);          off += (size_t)32 * NJOBS * 128 * 4;      // 0.66 MB

  k_transpose_cvt<<<dim3(N3 / 32, CCH / 32), 256, 0, stream>>>(W_qkv, Wt_qkv, CCH, N3);
  k_transpose_cvt<<<dim3(CCH / 32, CCH / 32), 256, 0, stream>>>(W_proj, Wt_proj, CCH, CCH);
  k_qkv_gemm<<<dim3(BT / 128, N3 / 128), 256, 0, stream>>>(x, Wt_qkv, b_qkv, Qb, Kb, Vt);
  k_attn<<<dim3(NJOBS, BB * HH), 256, 0, stream>>>(Qb, Kb, Vt, PO, Pm, Pl);
  k_attn_combine<<<dim3(TT / 128, BB * HH), 256, 0, stream>>>(PO, Pm, Pl, Yb);
  k_proj_gemm<<<dim3(BT / 128, CCH / 128), 256, 0, stream>>>(Yb, Wt_proj, b_proj, out);
}

// Round 3
// 140.044 us; speedup vs baseline: 1.4292x; 1.2606x over previous
//
#include <hip/hip_runtime.h>
#include <hip/hip_bf16.h>
#include <math.h>

#define BB 2
#define TT 2048
#define CCH 1024
#define HH 16
#define DD 64
#define BT (BB*TT)     // 4096
#define N3 (3*CCH)     // 3072
#define NJOBS 40       // sum over 16 q-tiles of ceil((qt+1)/4)

typedef __attribute__((ext_vector_type(8))) short short8;
typedef __attribute__((ext_vector_type(4))) float f32x4;
typedef __attribute__((ext_vector_type(16))) float f32x16;

__device__ __forceinline__ unsigned short f2bf(float f) {
  unsigned int u = __float_as_uint(f);
  unsigned int r = (u + 0x7FFFu + ((u >> 16) & 1u)) >> 16;  // RNE
  return (unsigned short)r;
}
__device__ __forceinline__ float bf2f(unsigned short u) {
  return __uint_as_float(((unsigned int)u) << 16);
}
__device__ __forceinline__ int cvtpk(float lo, float hi) {
  int r;
  asm("v_cvt_pk_bf16_f32 %0, %1, %2" : "=v"(r) : "v"(lo), "v"(hi));
  return r;
}
__device__ __forceinline__ void plswap(int &a, int &b) {
  // after: a = {a[0:31], b[0:31]}, b = {a[32:63], b[32:63]}
  asm("v_permlane32_swap_b32 %0, %1" : "+v"(a), "+v"(b));
}
// job-base for q-tile qt
__device__ __forceinline__ int jbase(int qt) {
  int a = qt >> 2, b = qt & 3;
  return qt + 2 * a * (a - 1) + a * b;
}

// ---------------- f32 -> bf16 flat convert ----------------
__global__ __launch_bounds__(256) void k_convert(const float* __restrict__ in,
                                                 unsigned short* __restrict__ out, int n8) {
  int i = blockIdx.x * 256 + threadIdx.x;
  if (i < n8) {
    const float4 a = *(const float4*)(in + (size_t)i * 8);
    const float4 b = *(const float4*)(in + (size_t)i * 8 + 4);
    short8 v;
    v[0] = f2bf(a.x); v[1] = f2bf(a.y); v[2] = f2bf(a.z); v[3] = f2bf(a.w);
    v[4] = f2bf(b.x); v[5] = f2bf(b.y); v[6] = f2bf(b.z); v[7] = f2bf(b.w);
    *(short8*)(out + (size_t)i * 8) = v;
  }
}

// ---------------- transpose + f32->bf16 convert: out[c][r] = in[r][c] ----------------
__global__ __launch_bounds__(256) void k_transpose_cvt(const float* __restrict__ in,
                                                       unsigned short* __restrict__ out,
                                                       int R, int Cn) {
  __shared__ float tile[32][33];
  int tc = blockIdx.x * 32;
  int tr = blockIdx.y * 32;
  int lx = threadIdx.x & 31;
  int ly = threadIdx.x >> 5;  // 0..7
#pragma unroll
  for (int i = 0; i < 32; i += 8)
    tile[ly + i][lx] = in[(size_t)(tr + ly + i) * Cn + tc + lx];
  __syncthreads();
#pragma unroll
  for (int i = 0; i < 32; i += 8)
    out[(size_t)(tc + ly + i) * R + tr + lx] = f2bf(tile[lx][ly + i]);
}

// ---------------- QKV GEMM: Xb[4096][1024] bf16 @ Wt[3072][1024] bf16 -> Q(scaled),K,Vt bf16 ----------------
__global__ __launch_bounds__(256) void k_qkv_gemm(const unsigned short* __restrict__ Xb,
                                                  const unsigned short* __restrict__ Wt,
                                                  const float* __restrict__ bias,
                                                  unsigned short* __restrict__ Qo,
                                                  unsigned short* __restrict__ Ko,
                                                  unsigned short* __restrict__ Vto) {
  __shared__ unsigned short As[128][40];
  __shared__ unsigned short Bs[128][40];
  int tid = threadIdx.x;
  int mb = blockIdx.x * 128;
  int nb = blockIdx.y * 128;
  int wid = tid >> 6, lane = tid & 63;
  int wr = (wid >> 1) * 64, wc = (wid & 1) * 64;
  int l15 = lane & 15, l4 = lane >> 4;
  f32x4 acc[4][4];
#pragma unroll
  for (int a = 0; a < 4; ++a)
#pragma unroll
    for (int b = 0; b < 4; ++b)
#pragma unroll
      for (int j = 0; j < 4; ++j) acc[a][b][j] = 0.0f;

  for (int kb = 0; kb < CCH; kb += 32) {
    __syncthreads();
#pragma unroll
    for (int i = 0; i < 2; ++i) {
      int idx = tid + i * 256;
      int row = idx >> 2, c8 = idx & 3;
      *(short8*)(&As[row][c8 * 8]) = *(const short8*)(Xb + (size_t)(mb + row) * CCH + kb + c8 * 8);
      *(short8*)(&Bs[row][c8 * 8]) = *(const short8*)(Wt + (size_t)(nb + row) * CCH + kb + c8 * 8);
    }
    __syncthreads();
    short8 af[4], bfr[4];
#pragma unroll
    for (int mt = 0; mt < 4; ++mt) af[mt] = *(const short8*)(&As[wr + mt * 16 + l15][l4 * 8]);
#pragma unroll
    for (int nt = 0; nt < 4; ++nt) bfr[nt] = *(const short8*)(&Bs[wc + nt * 16 + l15][l4 * 8]);
#pragma unroll
    for (int mt = 0; mt < 4; ++mt)
#pragma unroll
      for (int nt = 0; nt < 4; ++nt)
        acc[mt][nt] = __builtin_amdgcn_mfma_f32_16x16x32_bf16(af[mt], bfr[nt], acc[mt][nt], 0, 0, 0);
  }

#pragma unroll
  for (int mt = 0; mt < 4; ++mt) {
#pragma unroll
    for (int nt = 0; nt < 4; ++nt) {
      int gcol = nb + wc + nt * 16 + l15;        // 0..3071
      int which = gcol >> 10;
      int cc = gcol & 1023;
      int h = cc >> 6, d = cc & 63;
      float bv = bias[gcol];
#pragma unroll
      for (int j = 0; j < 4; ++j) {
        int grow = mb + wr + mt * 16 + l4 * 4 + j;  // 0..4095
        int b = grow >> 11, t = grow & 2047;
        float v = acc[mt][nt][j] + bv;
        size_t bh = (size_t)(b * HH + h);
        if (which == 0)      Qo[(bh * TT + t) * DD + d] = f2bf(v * 0.125f);  // fold sm_scale
        else if (which == 1) Ko[(bh * TT + t) * DD + d] = f2bf(v);
        else                 Vto[(bh * DD + d) * TT + t] = f2bf(v);
      }
    }
  }
}

// ---------------- causal flash attention: swapped QK^T, in-register softmax ----------------
// grid (NJOBS, B*H), 4 waves/block, each wave owns 32 q-rows. KVBLK=64 dbuf in LDS.
__global__ __launch_bounds__(256) void k_attn(const unsigned short* __restrict__ Qb,
                                              const unsigned short* __restrict__ Kb,
                                              const unsigned short* __restrict__ Vtb,
                                              unsigned short* __restrict__ PO,
                                              float* __restrict__ Pm,
                                              float* __restrict__ Pl) {
  __shared__ unsigned short Ks[2][64 * 64];   // [kv][d], XOR-swizzled 16B chunks
  __shared__ unsigned short Vs[2][64 * 64];   // [d][kv], XOR-swizzled 16B chunks
  int tid = threadIdx.x;
  int jx = blockIdx.x, bh = blockIdx.y;
  int qt = 0;
#pragma unroll
  for (int q = 1; q < 16; ++q)
    if (jx >= jbase(q)) qt = q;
  int chunk = jx - jbase(qt);
  int t0 = chunk * 8;
  int t1 = min(t0 + 8, (qt + 1) * 2);
  size_t job = (size_t)bh * NJOBS + jx;

  const unsigned short* Qp = Qb + (size_t)bh * TT * DD;
  const unsigned short* Kp = Kb + (size_t)bh * TT * DD;
  const unsigned short* Vp = Vtb + (size_t)bh * DD * TT;
  int wid = tid >> 6, lane = tid & 63;
  int l31 = lane & 31, h = lane >> 5;
  int q0 = qt * 128 + wid * 32;
  int qrow = q0 + l31;

  // Q as B-fragments: col q = l31, k = d = 16m + 8h + j  (Q pre-scaled by 1/8)
  short8 qf[4];
#pragma unroll
  for (int m = 0; m < 4; ++m)
    qf[m] = *(const short8*)(Qp + (size_t)qrow * DD + m * 16 + h * 8);

  // O^T accumulators: po[dt] rows d = 32dt + cr(r,h), col q = l31
  f32x16 po[2];
#pragma unroll
  for (int dt = 0; dt < 2; ++dt)
#pragma unroll
    for (int r = 0; r < 16; ++r) po[dt][r] = 0.0f;
  float mrun = -1e30f, lrun = 0.0f;

  // prologue: stage tile t0 into buffer 0 (512 chunks of 16B per 8KB tile)
  short8 rk[2], rv[2];
#pragma unroll
  for (int i = 0; i < 2; ++i) {
    int idx = tid + i * 256;
    int row = idx >> 3, c = idx & 7;
    rk[i] = *(const short8*)(Kp + (size_t)(t0 * 64 + row) * DD + c * 8);
    rv[i] = *(const short8*)(Vp + (size_t)row * TT + t0 * 64 + c * 8);
  }
#pragma unroll
  for (int i = 0; i < 2; ++i) {
    int idx = tid + i * 256;
    int row = idx >> 3, c = idx & 7;
    int off = row * 64 + ((c ^ (row & 7)) * 8);
    *(short8*)(&Ks[0][off]) = rk[i];
    *(short8*)(&Vs[0][off]) = rv[i];
  }

  int buf = 0;
  for (int t = t0; t < t1; ++t) {
    __syncthreads();
    int kvb = t * 64;
    bool havenext = (t + 1 < t1);
    if (havenext) {
      int kvb2 = (t + 1) * 64;
#pragma unroll
      for (int i = 0; i < 2; ++i) {
        int idx = tid + i * 256;
        int row = idx >> 3, c = idx & 7;
        rk[i] = *(const short8*)(Kp + (size_t)(kvb2 + row) * DD + c * 8);
        rv[i] = *(const short8*)(Vp + (size_t)row * TT + kvb2 + c * 8);
      }
    }

    if (kvb <= q0 + 31) {             // wave-uniform visit test
      // S^T = K · Q^T : st[t32] rows kv = 32*t32 + cr(r,h), col q = l31
      f32x16 st[2];
#pragma unroll
      for (int t32 = 0; t32 < 2; ++t32) {
#pragma unroll
        for (int r = 0; r < 16; ++r) st[t32][r] = 0.0f;
#pragma unroll
        for (int m = 0; m < 4; ++m) {
          int row = t32 * 32 + l31;
          int off = row * 64 + (((2 * m + h) ^ (row & 7)) * 8);
          short8 kf = *(const short8*)(&Ks[buf][off]);
          st[t32] = __builtin_amdgcn_mfma_f32_32x32x16_bf16(kf, qf[m], st[t32], 0, 0, 0);
        }
      }

      // causal mask (diagonal tiles only; wave-uniform branch)
      if (kvb + 63 > q0) {
#pragma unroll
        for (int t32 = 0; t32 < 2; ++t32)
#pragma unroll
          for (int r = 0; r < 16; ++r) {
            int kvg = kvb + t32 * 32 + (r & 3) + 8 * (r >> 2) + 4 * h;
            if (kvg > qrow) st[t32][r] = -1e30f;
          }
      }

      // row max: in-lane over 32 + one cross-half exchange
      float mx = -1e30f;
#pragma unroll
      for (int t32 = 0; t32 < 2; ++t32)
#pragma unroll
        for (int r = 0; r < 16; ++r) mx = fmaxf(mx, st[t32][r]);
      mx = fmaxf(mx, __shfl_xor(mx, 32));

      // defer-max rescale (T13)
      if (__any(mx - mrun > 8.0f)) {
        float mnew = fmaxf(mrun, mx);
        float alpha = __expf(mrun - mnew);
        lrun *= alpha;
#pragma unroll
        for (int dt = 0; dt < 2; ++dt)
#pragma unroll
          for (int r = 0; r < 16; ++r) po[dt][r] *= alpha;
        mrun = mnew;
      }

      // exp + row sum
      float sum = 0.0f;
#pragma unroll
      for (int t32 = 0; t32 < 2; ++t32)
#pragma unroll
        for (int r = 0; r < 16; ++r) {
          float p = __expf(st[t32][r] - mrun);
          st[t32][r] = p;
          sum += p;
        }
      sum += __shfl_xor(sum, 32);
      lrun += sum;

      // P -> bf16 B-fragments via cvt_pk + permlane32_swap (T12)
      short8 pf[4];
#pragma unroll
      for (int g = 0; g < 4; ++g) {
        int t32 = g >> 1, r0 = (g & 1) * 8;
        int a = cvtpk(st[t32][r0 + 0], st[t32][r0 + 1]);
        int b = cvtpk(st[t32][r0 + 4], st[t32][r0 + 5]);
        plswap(a, b);                 // a = word0 (kv 8h+0,1), b = word2 (kv 8h+4,5)
        int c = cvtpk(st[t32][r0 + 2], st[t32][r0 + 3]);
        int d = cvtpk(st[t32][r0 + 6], st[t32][r0 + 7]);
        plswap(c, d);                 // c = word1, d = word3
        union { int w[4]; short8 s; } u;
        u.w[0] = a; u.w[1] = c; u.w[2] = b; u.w[3] = d;
        pf[g] = u.s;
      }

      // O^T += V^T · P : po[dt] over kv groups g (16 each)
#pragma unroll
      for (int dt = 0; dt < 2; ++dt) {
#pragma unroll
        for (int g = 0; g < 4; ++g) {
          int row = dt * 32 + l31;
          int off = row * 64 + (((2 * g + h) ^ (row & 7)) * 8);
          short8 vf = *(const short8*)(&Vs[buf][off]);
          po[dt] = __builtin_amdgcn_mfma_f32_32x32x16_bf16(vf, pf[g], po[dt], 0, 0, 0);
        }
      }
    }

    if (havenext) {
#pragma unroll
      for (int i = 0; i < 2; ++i) {
        int idx = tid + i * 256;
        int row = idx >> 3, c = idx & 7;
        int off = row * 64 + ((c ^ (row & 7)) * 8);
        *(short8*)(&Ks[buf ^ 1][off]) = rk[i];
        *(short8*)(&Vs[buf ^ 1][off]) = rv[i];
      }
    }
    buf ^= 1;
  }

  // store unnormalized partial O^T (bf16 pairs) + m,l
  int wrow = wid * 32 + l31;
  size_t pobase = (job * 128 + wrow) * 64;
#pragma unroll
  for (int dt = 0; dt < 2; ++dt)
#pragma unroll
    for (int r = 0; r < 16; r += 2) {
      int d = dt * 32 + (r & 3) + 8 * (r >> 2) + 4 * h;
      int w = cvtpk(po[dt][r], po[dt][r + 1]);
      *(int*)(PO + pobase + d) = w;
    }
  if (h == 0) {
    Pm[job * 128 + wrow] = mrun;
    Pl[job * 128 + wrow] = lrun;
  }
}

// ---------------- combine partials -> Yb bf16 ----------------
__global__ __launch_bounds__(256) void k_attn_combine(const unsigned short* __restrict__ PO,
                                                      const float* __restrict__ Pm,
                                                      const float* __restrict__ Pl,
                                                      unsigned short* __restrict__ Y) {
  int qt = blockIdx.x, bh = blockIdx.y;
  int nc = (qt >> 2) + 1;
  size_t job0 = (size_t)bh * NJOBS + jbase(qt);
  int tid = threadIdx.x;
  int row = tid >> 1, half = tid & 1;

  float m[4], l[4];
  float M = -1e30f;
  for (int c = 0; c < nc; ++c) {
    m[c] = Pm[(job0 + c) * 128 + row];
    l[c] = Pl[(job0 + c) * 128 + row];
    M = fmaxf(M, m[c]);
  }
  float L = 0.0f, w[4];
  for (int c = 0; c < nc; ++c) {
    w[c] = __expf(m[c] - M);
    L += l[c] * w[c];
  }
  float inv = 1.0f / L;

  float acc[32];
#pragma unroll
  for (int j = 0; j < 32; ++j) acc[j] = 0.0f;
  for (int c = 0; c < nc; ++c) {
    const unsigned short* p = PO + ((job0 + c) * 128 + row) * 64 + half * 32;
    float wc = w[c];
#pragma unroll
    for (int k = 0; k < 4; ++k) {
      short8 v = *(const short8*)(p + k * 8);
#pragma unroll
      for (int j = 0; j < 8; ++j) acc[k * 8 + j] += wc * bf2f((unsigned short)v[j]);
    }
  }
  int b = bh >> 4, hh = bh & 15;
  int t = qt * 128 + row;
  unsigned short* yp = Y + ((size_t)(b * TT + t)) * CCH + hh * DD + half * 32;
#pragma unroll
  for (int k = 0; k < 4; ++k) {
    short8 wv;
#pragma unroll
    for (int j = 0; j < 8; ++j) wv[j] = (short)f2bf(acc[k * 8 + j] * inv);
    *(short8*)(yp + k * 8) = wv;
  }
}

// ---------------- proj GEMM: y[4096][1024] bf16 @ Wt_proj[1024][1024] bf16 + bias -> f32 out ----------------
__global__ __launch_bounds__(256) void k_proj_gemm(const unsigned short* __restrict__ Yb,
                                                   const unsigned short* __restrict__ Wt,
                                                   const float* __restrict__ bias,
                                                   float* __restrict__ Out) {
  __shared__ unsigned short As[128][40];
  __shared__ unsigned short Bs[128][40];
  int tid = threadIdx.x;
  int mb = blockIdx.x * 128;
  int nb = blockIdx.y * 128;
  int wid = tid >> 6, lane = tid & 63;
  int wr = (wid >> 1) * 64, wc = (wid & 1) * 64;
  int l15 = lane & 15, l4 = lane >> 4;
  f32x4 acc[4][4];
#pragma unroll
  for (int a = 0; a < 4; ++a)
#pragma unroll
    for (int b = 0; b < 4; ++b)
#pragma unroll
      for (int j = 0; j < 4; ++j) acc[a][b][j] = 0.0f;

  for (int kb = 0; kb < CCH; kb += 32) {
    __syncthreads();
#pragma unroll
    for (int i = 0; i < 2; ++i) {
      int idx = tid + i * 256;
      int row = idx >> 2, c8 = idx & 3;
      *(short8*)(&As[row][c8 * 8]) = *(const short8*)(Yb + (size_t)(mb + row) * CCH + kb + c8 * 8);
      *(short8*)(&Bs[row][c8 * 8]) = *(const short8*)(Wt + (size_t)(nb + row) * CCH + kb + c8 * 8);
    }
    __syncthreads();
    short8 af[4], bfr[4];
#pragma unroll
    for (int mt = 0; mt < 4; ++mt) af[mt] = *(const short8*)(&As[wr + mt * 16 + l15][l4 * 8]);
#pragma unroll
    for (int nt = 0; nt < 4; ++nt) bfr[nt] = *(const short8*)(&Bs[wc + nt * 16 + l15][l4 * 8]);
#pragma unroll
    for (int mt = 0; mt < 4; ++mt)
#pragma unroll
      for (int nt = 0; nt < 4; ++nt)
        acc[mt][nt] = __builtin_amdgcn_mfma_f32_16x16x32_bf16(af[mt], bfr[nt], acc[mt][nt], 0, 0, 0);
  }

#pragma unroll
  for (int mt = 0; mt < 4; ++mt) {
#pragma unroll
    for (int nt = 0; nt < 4; ++nt) {
      int gcol = nb + wc + nt * 16 + l15;
      float bv = bias[gcol];
#pragma unroll
      for (int j = 0; j < 4; ++j) {
        int grow = mb + wr + mt * 16 + l4 * 4 + j;
        Out[(size_t)grow * CCH + gcol] = acc[mt][nt][j] + bv;
      }
    }
  }
}

extern "C" void kernel_launch(void* const* d_in, const int* in_sizes, int n_in,
                              void* d_out, int out_size, void* d_ws, size_t ws_size,
                              hipStream_t stream) {
  const float* x      = (const float*)d_in[0];
  const float* W_qkv  = (const float*)d_in[1];
  const float* b_qkv  = (const float*)d_in[2];
  const float* W_proj = (const float*)d_in[3];
  const float* b_proj = (const float*)d_in[4];
  float* out = (float*)d_out;

  char* ws = (char*)d_ws;
  size_t off = 0;
  unsigned short* Wt_qkv  = (unsigned short*)(ws + off); off += (size_t)N3 * CCH * 2;   // 6.3 MB
  unsigned short* Wt_proj = (unsigned short*)(ws + off); off += (size_t)CCH * CCH * 2;  // 2.1 MB
  unsigned short* Xb      = (unsigned short*)(ws + off); off += (size_t)BT * CCH * 2;   // 8.4 MB
  unsigned short* Qb      = (unsigned short*)(ws + off); off += (size_t)BT * CCH * 2;   // 8.4 MB
  unsigned short* Kb      = (unsigned short*)(ws + off); off += (size_t)BT * CCH * 2;   // 8.4 MB
  unsigned short* Vt      = (unsigned short*)(ws + off); off += (size_t)BT * CCH * 2;   // 8.4 MB
  unsigned short* Yb      = (unsigned short*)(ws + off); off += (size_t)BT * CCH * 2;   // 8.4 MB
  unsigned short* PO      = (unsigned short*)(ws + off); off += (size_t)32 * NJOBS * 128 * 64 * 2; // 21 MB
  float*          Pm      = (float*)(ws + off);          off += (size_t)32 * NJOBS * 128 * 4;
  float*          Pl      = (float*)(ws + off);          off += (size_t)32 * NJOBS * 128 * 4;

  k_convert<<<dim3(BT * CCH / 8 / 256), 256, 0, stream>>>(x, Xb, BT * CCH / 8);
  k_transpose_cvt<<<dim3(N3 / 32, CCH / 32), 256, 0, stream>>>(W_qkv, Wt_qkv, CCH, N3);
  k_transpose_cvt<<<dim3(CCH / 32, CCH / 32), 256, 0, stream>>>(W_proj, Wt_proj, CCH, CCH);
  k_qkv_gemm<<<dim3(BT / 128, N3 / 128), 256, 0, stream>>>(Xb, Wt_qkv, b_qkv, Qb, Kb, Vt);
  k_attn<<<dim3(NJOBS, BB * HH), 256, 0, stream>>>(Qb, Kb, Vt, PO, Pm, Pl);
  k_attn_combine<<<dim3(TT / 128, BB * HH), 256, 0, stream>>>(PO, Pm, Pl, Yb);
  k_proj_gemm<<<dim3(BT / 128, CCH / 128), 256, 0, stream>>>(Yb, Wt_proj, b_proj, out);
}

// Round 4
// 130.685 us; speedup vs baseline: 1.5315x; 1.0716x over previous
//
#include <hip/hip_runtime.h>
#include <hip/hip_bf16.h>
#include <math.h>

#define BB 2
#define TT 2048
#define CCH 1024
#define HH 16
#define DD 64
#define BT (BB*TT)     // 4096
#define N3 (3*CCH)     // 3072
#define NJOBS 40       // sum over 16 q-tiles of ceil((qt+1)/4)

typedef __attribute__((ext_vector_type(8))) short short8;
typedef __attribute__((ext_vector_type(4))) float f32x4;
typedef __attribute__((ext_vector_type(16))) float f32x16;

__device__ __forceinline__ unsigned short f2bf(float f) {
  unsigned int u = __float_as_uint(f);
  unsigned int r = (u + 0x7FFFu + ((u >> 16) & 1u)) >> 16;  // RNE
  return (unsigned short)r;
}
__device__ __forceinline__ float bf2f(unsigned short u) {
  return __uint_as_float(((unsigned int)u) << 16);
}
__device__ __forceinline__ int cvtpk(float lo, float hi) {
  int r;
  asm("v_cvt_pk_bf16_f32 %0, %1, %2" : "=v"(r) : "v"(lo), "v"(hi));
  return r;
}
__device__ __forceinline__ void plswap(int &a, int &b) {
  asm("v_permlane32_swap_b32 %0, %1" : "+v"(a), "+v"(b));
}
__device__ __forceinline__ void gload_lds16(const unsigned short* g, unsigned short* l) {
  __builtin_amdgcn_global_load_lds((const __attribute__((address_space(1))) void*)g,
                                   (__attribute__((address_space(3))) void*)l, 16, 0, 0);
}
// job-base for q-tile qt
__device__ __forceinline__ int jbase(int qt) {
  int a = qt >> 2, b = qt & 3;
  return qt + 2 * a * (a - 1) + a * b;
}

// ---------------- f32 -> bf16 flat convert ----------------
__global__ __launch_bounds__(256) void k_convert(const float* __restrict__ in,
                                                 unsigned short* __restrict__ out, int n8) {
  int i = blockIdx.x * 256 + threadIdx.x;
  if (i < n8) {
    const float4 a = *(const float4*)(in + (size_t)i * 8);
    const float4 b = *(const float4*)(in + (size_t)i * 8 + 4);
    short8 v;
    v[0] = f2bf(a.x); v[1] = f2bf(a.y); v[2] = f2bf(a.z); v[3] = f2bf(a.w);
    v[4] = f2bf(b.x); v[5] = f2bf(b.y); v[6] = f2bf(b.z); v[7] = f2bf(b.w);
    *(short8*)(out + (size_t)i * 8) = v;
  }
}

// ---------------- transpose + f32->bf16 convert: out[c][r] = in[r][c] ----------------
__global__ __launch_bounds__(256) void k_transpose_cvt(const float* __restrict__ in,
                                                       unsigned short* __restrict__ out,
                                                       int R, int Cn) {
  __shared__ float tile[32][33];
  int tc = blockIdx.x * 32;
  int tr = blockIdx.y * 32;
  int lx = threadIdx.x & 31;
  int ly = threadIdx.x >> 5;  // 0..7
#pragma unroll
  for (int i = 0; i < 32; i += 8)
    tile[ly + i][lx] = in[(size_t)(tr + ly + i) * Cn + tc + lx];
  __syncthreads();
#pragma unroll
  for (int i = 0; i < 32; i += 8)
    out[(size_t)(tc + ly + i) * R + tr + lx] = f2bf(tile[lx][ly + i]);
}

// ---------------- QKV GEMM (m97 pattern): Xb bf16 @ Wt bf16 -> Q(scaled),K,Vt bf16 ----------------
__global__ __launch_bounds__(256) void k_qkv_gemm(const unsigned short* __restrict__ Xb,
                                                  const unsigned short* __restrict__ Wt,
                                                  const float* __restrict__ bias,
                                                  unsigned short* __restrict__ Qo,
                                                  unsigned short* __restrict__ Ko,
                                                  unsigned short* __restrict__ Vto) {
  __shared__ __align__(16) unsigned short As[128 * 32];
  __shared__ __align__(16) unsigned short Bs[128 * 32];
  int tid = threadIdx.x;
  int mb = blockIdx.x * 128;
  int nb = blockIdx.y * 128;
  int wid = tid >> 6, lane = tid & 63;
  int wr = (wid >> 1) * 64, wc = (wid & 1) * 64;
  int l15 = lane & 15, l4 = lane >> 4;
  int l16 = lane >> 2, lc = (lane & 3) * 8;   // staging row-within-16 / col
  f32x4 acc[4][4];
#pragma unroll
  for (int a = 0; a < 4; ++a)
#pragma unroll
    for (int b = 0; b < 4; ++b)
#pragma unroll
      for (int j = 0; j < 4; ++j) acc[a][b][j] = 0.0f;

  for (int kb = 0; kb < CCH; kb += 32) {
    // stage: direct global->LDS (wave-uniform LDS base + lane*16B, linear layout)
#pragma unroll
    for (int i = 0; i < 2; ++i) {
      int arow = wid * 32 + i * 16;
      gload_lds16(Xb + (size_t)(mb + arow + l16) * CCH + kb + lc, &As[arow * 32]);
      gload_lds16(Wt + (size_t)(nb + arow + l16) * CCH + kb + lc, &Bs[arow * 32]);
    }
    __syncthreads();   // drains vmcnt, data visible
    short8 af[4], bfr[4];
#pragma unroll
    for (int mt = 0; mt < 4; ++mt) af[mt] = *(const short8*)(&As[(wr + mt * 16 + l15) * 32 + l4 * 8]);
#pragma unroll
    for (int nt = 0; nt < 4; ++nt) bfr[nt] = *(const short8*)(&Bs[(wc + nt * 16 + l15) * 32 + l4 * 8]);
#pragma unroll
    for (int mt = 0; mt < 4; ++mt)
#pragma unroll
      for (int nt = 0; nt < 4; ++nt)
        acc[mt][nt] = __builtin_amdgcn_mfma_f32_16x16x32_bf16(af[mt], bfr[nt], acc[mt][nt], 0, 0, 0);
    __syncthreads();   // all waves done reading before next stage
  }

#pragma unroll
  for (int mt = 0; mt < 4; ++mt) {
#pragma unroll
    for (int nt = 0; nt < 4; ++nt) {
      int gcol = nb + wc + nt * 16 + l15;        // 0..3071
      int which = gcol >> 10;
      int cc = gcol & 1023;
      int h = cc >> 6, d = cc & 63;
      float bv = bias[gcol];
#pragma unroll
      for (int j = 0; j < 4; ++j) {
        int grow = mb + wr + mt * 16 + l4 * 4 + j;  // 0..4095
        int b = grow >> 11, t = grow & 2047;
        float v = acc[mt][nt][j] + bv;
        size_t bh = (size_t)(b * HH + h);
        if (which == 0)      Qo[(bh * TT + t) * DD + d] = f2bf(v * 0.125f);  // fold sm_scale
        else if (which == 1) Ko[(bh * TT + t) * DD + d] = f2bf(v);
        else                 Vto[(bh * DD + d) * TT + t] = f2bf(v);
      }
    }
  }
}

// ---------------- causal flash attention: swapped QK^T, in-register softmax ----------------
__global__ __launch_bounds__(256) void k_attn(const unsigned short* __restrict__ Qb,
                                              const unsigned short* __restrict__ Kb,
                                              const unsigned short* __restrict__ Vtb,
                                              unsigned short* __restrict__ PO,
                                              float* __restrict__ Pm,
                                              float* __restrict__ Pl) {
  __shared__ unsigned short Ks[2][64 * 64];   // [kv][d], XOR-swizzled 16B chunks
  __shared__ unsigned short Vs[2][64 * 64];   // [d][kv], XOR-swizzled 16B chunks
  int tid = threadIdx.x;
  int jx = blockIdx.x, bh = blockIdx.y;
  int qt = 0;
#pragma unroll
  for (int q = 1; q < 16; ++q)
    if (jx >= jbase(q)) qt = q;
  int chunk = jx - jbase(qt);
  int t0 = chunk * 8;
  int t1 = min(t0 + 8, (qt + 1) * 2);
  size_t job = (size_t)bh * NJOBS + jx;

  const unsigned short* Qp = Qb + (size_t)bh * TT * DD;
  const unsigned short* Kp = Kb + (size_t)bh * TT * DD;
  const unsigned short* Vp = Vtb + (size_t)bh * DD * TT;
  int wid = tid >> 6, lane = tid & 63;
  int l31 = lane & 31, h = lane >> 5;
  int q0 = qt * 128 + wid * 32;
  int qrow = q0 + l31;

  short8 qf[4];
#pragma unroll
  for (int m = 0; m < 4; ++m)
    qf[m] = *(const short8*)(Qp + (size_t)qrow * DD + m * 16 + h * 8);

  f32x16 po[2];
#pragma unroll
  for (int dt = 0; dt < 2; ++dt)
#pragma unroll
    for (int r = 0; r < 16; ++r) po[dt][r] = 0.0f;
  float mrun = -1e30f, lrun = 0.0f;

  short8 rk[2], rv[2];
#pragma unroll
  for (int i = 0; i < 2; ++i) {
    int idx = tid + i * 256;
    int row = idx >> 3, c = idx & 7;
    rk[i] = *(const short8*)(Kp + (size_t)(t0 * 64 + row) * DD + c * 8);
    rv[i] = *(const short8*)(Vp + (size_t)row * TT + t0 * 64 + c * 8);
  }
#pragma unroll
  for (int i = 0; i < 2; ++i) {
    int idx = tid + i * 256;
    int row = idx >> 3, c = idx & 7;
    int off = row * 64 + ((c ^ (row & 7)) * 8);
    *(short8*)(&Ks[0][off]) = rk[i];
    *(short8*)(&Vs[0][off]) = rv[i];
  }

  int buf = 0;
  for (int t = t0; t < t1; ++t) {
    __syncthreads();
    int kvb = t * 64;
    bool havenext = (t + 1 < t1);
    if (havenext) {
      int kvb2 = (t + 1) * 64;
#pragma unroll
      for (int i = 0; i < 2; ++i) {
        int idx = tid + i * 256;
        int row = idx >> 3, c = idx & 7;
        rk[i] = *(const short8*)(Kp + (size_t)(kvb2 + row) * DD + c * 8);
        rv[i] = *(const short8*)(Vp + (size_t)row * TT + kvb2 + c * 8);
      }
    }

    if (kvb <= q0 + 31) {
      f32x16 st[2];
      __builtin_amdgcn_s_setprio(1);
#pragma unroll
      for (int t32 = 0; t32 < 2; ++t32) {
#pragma unroll
        for (int r = 0; r < 16; ++r) st[t32][r] = 0.0f;
#pragma unroll
        for (int m = 0; m < 4; ++m) {
          int row = t32 * 32 + l31;
          int off = row * 64 + (((2 * m + h) ^ (row & 7)) * 8);
          short8 kf = *(const short8*)(&Ks[buf][off]);
          st[t32] = __builtin_amdgcn_mfma_f32_32x32x16_bf16(kf, qf[m], st[t32], 0, 0, 0);
        }
      }
      __builtin_amdgcn_s_setprio(0);

      if (kvb + 63 > q0) {
#pragma unroll
        for (int t32 = 0; t32 < 2; ++t32)
#pragma unroll
          for (int r = 0; r < 16; ++r) {
            int kvg = kvb + t32 * 32 + (r & 3) + 8 * (r >> 2) + 4 * h;
            if (kvg > qrow) st[t32][r] = -1e30f;
          }
      }

      float mx = -1e30f;
#pragma unroll
      for (int t32 = 0; t32 < 2; ++t32)
#pragma unroll
        for (int r = 0; r < 16; ++r) mx = fmaxf(mx, st[t32][r]);
      mx = fmaxf(mx, __shfl_xor(mx, 32));

      if (__any(mx - mrun > 8.0f)) {
        float mnew = fmaxf(mrun, mx);
        float alpha = __expf(mrun - mnew);
        lrun *= alpha;
#pragma unroll
        for (int dt = 0; dt < 2; ++dt)
#pragma unroll
          for (int r = 0; r < 16; ++r) po[dt][r] *= alpha;
        mrun = mnew;
      }

      float sum = 0.0f;
#pragma unroll
      for (int t32 = 0; t32 < 2; ++t32)
#pragma unroll
        for (int r = 0; r < 16; ++r) {
          float p = __expf(st[t32][r] - mrun);
          st[t32][r] = p;
          sum += p;
        }
      sum += __shfl_xor(sum, 32);
      lrun += sum;

      short8 pf[4];
#pragma unroll
      for (int g = 0; g < 4; ++g) {
        int t32 = g >> 1, r0 = (g & 1) * 8;
        int a = cvtpk(st[t32][r0 + 0], st[t32][r0 + 1]);
        int b = cvtpk(st[t32][r0 + 4], st[t32][r0 + 5]);
        plswap(a, b);
        int c = cvtpk(st[t32][r0 + 2], st[t32][r0 + 3]);
        int d = cvtpk(st[t32][r0 + 6], st[t32][r0 + 7]);
        plswap(c, d);
        union { int w[4]; short8 s; } u;
        u.w[0] = a; u.w[1] = c; u.w[2] = b; u.w[3] = d;
        pf[g] = u.s;
      }

      __builtin_amdgcn_s_setprio(1);
#pragma unroll
      for (int dt = 0; dt < 2; ++dt) {
#pragma unroll
        for (int g = 0; g < 4; ++g) {
          int row = dt * 32 + l31;
          int off = row * 64 + (((2 * g + h) ^ (row & 7)) * 8);
          short8 vf = *(const short8*)(&Vs[buf][off]);
          po[dt] = __builtin_amdgcn_mfma_f32_32x32x16_bf16(vf, pf[g], po[dt], 0, 0, 0);
        }
      }
      __builtin_amdgcn_s_setprio(0);
    }

    if (havenext) {
#pragma unroll
      for (int i = 0; i < 2; ++i) {
        int idx = tid + i * 256;
        int row = idx >> 3, c = idx & 7;
        int off = row * 64 + ((c ^ (row & 7)) * 8);
        *(short8*)(&Ks[buf ^ 1][off]) = rk[i];
        *(short8*)(&Vs[buf ^ 1][off]) = rv[i];
      }
    }
    buf ^= 1;
  }

  int wrow = wid * 32 + l31;
  size_t pobase = (job * 128 + wrow) * 64;
#pragma unroll
  for (int dt = 0; dt < 2; ++dt)
#pragma unroll
    for (int r = 0; r < 16; r += 2) {
      int d = dt * 32 + (r & 3) + 8 * (r >> 2) + 4 * h;
      int w = cvtpk(po[dt][r], po[dt][r + 1]);
      *(int*)(PO + pobase + d) = w;
    }
  if (h == 0) {
    Pm[job * 128 + wrow] = mrun;
    Pl[job * 128 + wrow] = lrun;
  }
}

// ---------------- combine partials -> Yb bf16 ----------------
__global__ __launch_bounds__(256) void k_attn_combine(const unsigned short* __restrict__ PO,
                                                      const float* __restrict__ Pm,
                                                      const float* __restrict__ Pl,
                                                      unsigned short* __restrict__ Y) {
  int qt = blockIdx.x, bh = blockIdx.y;
  int nc = (qt >> 2) + 1;
  size_t job0 = (size_t)bh * NJOBS + jbase(qt);
  int tid = threadIdx.x;
  int row = tid >> 1, half = tid & 1;

  float m[4], l[4];
  float M = -1e30f;
  for (int c = 0; c < nc; ++c) {
    m[c] = Pm[(job0 + c) * 128 + row];
    l[c] = Pl[(job0 + c) * 128 + row];
    M = fmaxf(M, m[c]);
  }
  float L = 0.0f, w[4];
  for (int c = 0; c < nc; ++c) {
    w[c] = __expf(m[c] - M);
    L += l[c] * w[c];
  }
  float inv = 1.0f / L;

  float acc[32];
#pragma unroll
  for (int j = 0; j < 32; ++j) acc[j] = 0.0f;
  for (int c = 0; c < nc; ++c) {
    const unsigned short* p = PO + ((job0 + c) * 128 + row) * 64 + half * 32;
    float wc = w[c];
#pragma unroll
    for (int k = 0; k < 4; ++k) {
      short8 v = *(const short8*)(p + k * 8);
#pragma unroll
      for (int j = 0; j < 8; ++j) acc[k * 8 + j] += wc * bf2f((unsigned short)v[j]);
    }
  }
  int b = bh >> 4, hh = bh & 15;
  int t = qt * 128 + row;
  unsigned short* yp = Y + ((size_t)(b * TT + t)) * CCH + hh * DD + half * 32;
#pragma unroll
  for (int k = 0; k < 4; ++k) {
    short8 wv;
#pragma unroll
    for (int j = 0; j < 8; ++j) wv[j] = (short)f2bf(acc[k * 8 + j] * inv);
    *(short8*)(yp + k * 8) = wv;
  }
}

// ---------------- proj GEMM (m97 pattern): Yb bf16 @ Wt_proj bf16 + bias -> f32 out ----------------
__global__ __launch_bounds__(256) void k_proj_gemm(const unsigned short* __restrict__ Yb,
                                                   const unsigned short* __restrict__ Wt,
                                                   const float* __restrict__ bias,
                                                   float* __restrict__ Out) {
  __shared__ __align__(16) unsigned short As[128 * 32];
  __shared__ __align__(16) unsigned short Bs[128 * 32];
  int tid = threadIdx.x;
  int mb = blockIdx.x * 128;
  int nb = blockIdx.y * 128;
  int wid = tid >> 6, lane = tid & 63;
  int wr = (wid >> 1) * 64, wc = (wid & 1) * 64;
  int l15 = lane & 15, l4 = lane >> 4;
  int l16 = lane >> 2, lc = (lane & 3) * 8;
  f32x4 acc[4][4];
#pragma unroll
  for (int a = 0; a < 4; ++a)
#pragma unroll
    for (int b = 0; b < 4; ++b)
#pragma unroll
      for (int j = 0; j < 4; ++j) acc[a][b][j] = 0.0f;

  for (int kb = 0; kb < CCH; kb += 32) {
#pragma unroll
    for (int i = 0; i < 2; ++i) {
      int arow = wid * 32 + i * 16;
      gload_lds16(Yb + (size_t)(mb + arow + l16) * CCH + kb + lc, &As[arow * 32]);
      gload_lds16(Wt + (size_t)(nb + arow + l16) * CCH + kb + lc, &Bs[arow * 32]);
    }
    __syncthreads();
    short8 af[4], bfr[4];
#pragma unroll
    for (int mt = 0; mt < 4; ++mt) af[mt] = *(const short8*)(&As[(wr + mt * 16 + l15) * 32 + l4 * 8]);
#pragma unroll
    for (int nt = 0; nt < 4; ++nt) bfr[nt] = *(const short8*)(&Bs[(wc + nt * 16 + l15) * 32 + l4 * 8]);
#pragma unroll
    for (int mt = 0; mt < 4; ++mt)
#pragma unroll
      for (int nt = 0; nt < 4; ++nt)
        acc[mt][nt] = __builtin_amdgcn_mfma_f32_16x16x32_bf16(af[mt], bfr[nt], acc[mt][nt], 0, 0, 0);
    __syncthreads();
  }

#pragma unroll
  for (int mt = 0; mt < 4; ++mt) {
#pragma unroll
    for (int nt = 0; nt < 4; ++nt) {
      int gcol = nb + wc + nt * 16 + l15;
      float bv = bias[gcol];
#pragma unroll
      for (int j = 0; j < 4; ++j) {
        int grow = mb + wr + mt * 16 + l4 * 4 + j;
        Out[(size_t)grow * CCH + gcol] = acc[mt][nt][j] + bv;
      }
    }
  }
}

extern "C" void kernel_launch(void* const* d_in, const int* in_sizes, int n_in,
                              void* d_out, int out_size, void* d_ws, size_t ws_size,
                              hipStream_t stream) {
  const float* x      = (const float*)d_in[0];
  const float* W_qkv  = (const float*)d_in[1];
  const float* b_qkv  = (const float*)d_in[2];
  const float* W_proj = (const float*)d_in[3];
  const float* b_proj = (const float*)d_in[4];
  float* out = (float*)d_out;

  char* ws = (char*)d_ws;
  size_t off = 0;
  unsigned short* Wt_qkv  = (unsigned short*)(ws + off); off += (size_t)N3 * CCH * 2;   // 6.3 MB
  unsigned short* Wt_proj = (unsigned short*)(ws + off); off += (size_t)CCH * CCH * 2;  // 2.1 MB
  unsigned short* Xb      = (unsigned short*)(ws + off); off += (size_t)BT * CCH * 2;   // 8.4 MB
  unsigned short* Qb      = (unsigned short*)(ws + off); off += (size_t)BT * CCH * 2;   // 8.4 MB
  unsigned short* Kb      = (unsigned short*)(ws + off); off += (size_t)BT * CCH * 2;   // 8.4 MB
  unsigned short* Vt      = (unsigned short*)(ws + off); off += (size_t)BT * CCH * 2;   // 8.4 MB
  unsigned short* Yb      = (unsigned short*)(ws + off); off += (size_t)BT * CCH * 2;   // 8.4 MB
  unsigned short* PO      = (unsigned short*)(ws + off); off += (size_t)32 * NJOBS * 128 * 64 * 2; // 21 MB
  float*          Pm      = (float*)(ws + off);          off += (size_t)32 * NJOBS * 128 * 4;
  float*          Pl      = (float*)(ws + off);          off += (size_t)32 * NJOBS * 128 * 4;

  k_convert<<<dim3(BT * CCH / 8 / 256), 256, 0, stream>>>(x, Xb, BT * CCH / 8);
  k_transpose_cvt<<<dim3(N3 / 32, CCH / 32), 256, 0, stream>>>(W_qkv, Wt_qkv, CCH, N3);
  k_transpose_cvt<<<dim3(CCH / 32, CCH / 32), 256, 0, stream>>>(W_proj, Wt_proj, CCH, CCH);
  k_qkv_gemm<<<dim3(BT / 128, N3 / 128), 256, 0, stream>>>(Xb, Wt_qkv, b_qkv, Qb, Kb, Vt);
  k_attn<<<dim3(NJOBS, BB * HH), 256, 0, stream>>>(Qb, Kb, Vt, PO, Pm, Pl);
  k_attn_combine<<<dim3(TT / 128, BB * HH), 256, 0, stream>>>(PO, Pm, Pl, Yb);
  k_proj_gemm<<<dim3(BT / 128, CCH / 128), 256, 0, stream>>>(Yb, Wt_proj, b_proj, out);
}